// Round 16
// baseline (105.452 us; speedup 1.0000x reference)
//
#include <hip/hip_runtime.h>

#define NH 8
#define ND 64
#define NM 32
#define NCH 32   // sub-chunk size
#define NC 32    // num sub-chunks

typedef float f32x4 __attribute__((ext_vector_type(4)));

// ---- 16-lane-group allreduce, pure VALU butterfly (no readlane) ----
__device__ __forceinline__ float grp16_sum(float x) {
    x += __int_as_float(__builtin_amdgcn_update_dpp(0, __float_as_int(x), 0xB1, 0xf, 0xf, false));
    x += __int_as_float(__builtin_amdgcn_update_dpp(0, __float_as_int(x), 0x4E, 0xf, 0xf, false));
    x += __int_as_float(__builtin_amdgcn_update_dpp(0, __float_as_int(x), 0x141, 0xf, 0xf, false));
    x += __int_as_float(__builtin_amdgcn_update_dpp(0, __float_as_int(x), 0x140, 0xf, 0xf, false));
    return x;
}

// One kernel, decoupled lookback: intra-scan -> publish -> wait preds -> prefix -> final-scan.
// 256 blocks x 512 threads, cooperative launch for co-residency (no grid.sync used).
__global__ __launch_bounds__(512) void fused_kernel(
    const float* __restrict__ A_bar, const float* __restrict__ K,
    const float* __restrict__ V, const float* __restrict__ beta,
    int* __restrict__ flags, float* __restrict__ totalA,
    float* __restrict__ buf, float* __restrict__ Y)
{
    __shared__ float K_l[NCH][ND], A_l[NCH][ND], V_l[NCH][ND], b_l[NCH];
    const int gh = blockIdx.x;          // g*NH + hh
    const int hh = gh & (NH - 1);
    const int g  = gh >> 3;
    const int tid = threadIdx.x;

    {   // stage chunk into LDS (512 float4 stagers per array)
        const int f = tid * 4;
        const int t = f >> 6, off = f & 63;
        const int row = ((g * NCH + t) * NH + hh) * 64 + off;
        *(float4*)&K_l[t][off] = *(const float4*)(K + row);
        *(float4*)&A_l[t][off] = *(const float4*)(A_bar + row);
        *(float4*)&V_l[t][off] = *(const float4*)(V + row);
        if (tid < NCH) b_l[tid] = beta[(g * NCH + tid) * NH + hh];
        __syncthreads();
    }

    const int lane = tid & 63;
    const int r = lane >> 4, j = lane & 15;
    const int m = (tid >> 6) * 4 + r;               // 0..31
    const int base_m = gh * NM + m;                 // entry id

    // ---- phase 1: intra scan (h0 = 0), track cumA; publish buf/totalA ----
    {
        float hr0 = 0.f, hr1 = 0.f, hr2 = 0.f, hr3 = 0.f;
        float hi0 = 0.f, hi1 = 0.f, hi2 = 0.f, hi3 = 0.f;
        float cr = 1.f, ci = 0.f;

#pragma unroll 4
        for (int t = 0; t < NCH; ++t) {
            const float4 k4 = *(const float4*)(&K_l[t][4 * j]);
            const float2 a2 = *(const float2*)(&A_l[t][2 * m]);
            const float2 v2 = *(const float2*)(&V_l[t][2 * m]);
            const float  b  = b_l[t];

            float sr = (hr0 * k4.x + hr1 * k4.y) + (hr2 * k4.z + hr3 * k4.w);
            float si = (hi0 * k4.x + hi1 * k4.y) + (hi2 * k4.z + hi3 * k4.w);
            sr = grp16_sum(sr);
            si = grp16_sum(si);

            const float bk0 = b * k4.x, bk1 = b * k4.y, bk2 = b * k4.z, bk3 = b * k4.w;
            float tr, ti;
            tr = hr0 - bk0 * sr; ti = hi0 - bk0 * si;
            hr0 = a2.x * tr - a2.y * ti + bk0 * v2.x;
            hi0 = a2.x * ti + a2.y * tr + bk0 * v2.y;
            tr = hr1 - bk1 * sr; ti = hi1 - bk1 * si;
            hr1 = a2.x * tr - a2.y * ti + bk1 * v2.x;
            hi1 = a2.x * ti + a2.y * tr + bk1 * v2.y;
            tr = hr2 - bk2 * sr; ti = hi2 - bk2 * si;
            hr2 = a2.x * tr - a2.y * ti + bk2 * v2.x;
            hi2 = a2.x * ti + a2.y * tr + bk2 * v2.y;
            tr = hr3 - bk3 * sr; ti = hi3 - bk3 * si;
            hr3 = a2.x * tr - a2.y * ti + bk3 * v2.x;
            hi3 = a2.x * ti + a2.y * tr + bk3 * v2.y;

            const float n = cr * a2.x - ci * a2.y;
            ci = cr * a2.y + ci * a2.x;
            cr = n;
        }

        *(float4*)&buf[base_m * 128 + 4 * j]      = make_float4(hr0, hr1, hr2, hr3);
        *(float4*)&buf[base_m * 128 + 64 + 4 * j] = make_float4(hi0, hi1, hi2, hi3);
        if (j == 0) {
            totalA[2 * base_m]     = cr;
            totalA[2 * base_m + 1] = ci;
        }
    }

    __syncthreads();                    // all block stores drained (vmcnt(0) before barrier)
    if (tid == 0) {
        __threadfence();                // device-scope fence: L2 writeback for cross-XCD visibility
        __hip_atomic_store(&flags[gh], 1, __ATOMIC_RELEASE, __HIP_MEMORY_SCOPE_AGENT);
    }

    // ---- phase 2: wait for predecessors, fold prefix s = A*s + H over gg < g ----
    if (tid == 0) {
        for (int gg = 0; gg < g; ++gg) {
            const int fidx = gg * NH + hh;
            while (__hip_atomic_load(&flags[fidx], __ATOMIC_ACQUIRE,
                                     __HIP_MEMORY_SCOPE_AGENT) == 0)
                __builtin_amdgcn_s_sleep(8);
        }
    }
    __syncthreads();                    // acquire + invalidate ordered before everyone's loads

    float sr0 = 0.f, sr1 = 0.f, sr2 = 0.f, sr3 = 0.f;
    float si0 = 0.f, si1 = 0.f, si2 = 0.f, si3 = 0.f;
    for (int gg = 0; gg < g; ++gg) {
        const int e = (gg * NH + hh) * NM + m;
        const float ar = totalA[2 * e], ai = totalA[2 * e + 1];
        const float4 fre = *(const float4*)&buf[e * 128 + 4 * j];
        const float4 fim = *(const float4*)&buf[e * 128 + 64 + 4 * j];
        float n;
        n = ar * sr0 - ai * si0 + fre.x;  si0 = ar * si0 + ai * sr0 + fim.x;  sr0 = n;
        n = ar * sr1 - ai * si1 + fre.y;  si1 = ar * si1 + ai * sr1 + fim.y;  sr1 = n;
        n = ar * sr2 - ai * si2 + fre.z;  si2 = ar * si2 + ai * sr2 + fim.z;  sr2 = n;
        n = ar * sr3 - ai * si3 + fre.w;  si3 = ar * si3 + ai * sr3 + fim.w;  sr3 = n;
    }

    // ---- phase 3: scan with init = s_in (chunk still in LDS); state IS the output ----
    {
        float hr0 = sr0, hr1 = sr1, hr2 = sr2, hr3 = sr3;
        float hi0 = si0, hi1 = si1, hi2 = si2, hi3 = si3;
        const int base_l = g * NCH;

#pragma unroll 4
        for (int t = 0; t < NCH; ++t) {
            const float4 k4 = *(const float4*)(&K_l[t][4 * j]);
            const float2 a2 = *(const float2*)(&A_l[t][2 * m]);
            const float2 v2 = *(const float2*)(&V_l[t][2 * m]);
            const float  b  = b_l[t];

            float sr = (hr0 * k4.x + hr1 * k4.y) + (hr2 * k4.z + hr3 * k4.w);
            float si = (hi0 * k4.x + hi1 * k4.y) + (hi2 * k4.z + hi3 * k4.w);
            sr = grp16_sum(sr);
            si = grp16_sum(si);

            const float bk0 = b * k4.x, bk1 = b * k4.y, bk2 = b * k4.z, bk3 = b * k4.w;
            float tr, ti;
            tr = hr0 - bk0 * sr; ti = hi0 - bk0 * si;
            hr0 = a2.x * tr - a2.y * ti + bk0 * v2.x;
            hi0 = a2.x * ti + a2.y * tr + bk0 * v2.y;
            tr = hr1 - bk1 * sr; ti = hi1 - bk1 * si;
            hr1 = a2.x * tr - a2.y * ti + bk1 * v2.x;
            hi1 = a2.x * ti + a2.y * tr + bk1 * v2.y;
            tr = hr2 - bk2 * sr; ti = hi2 - bk2 * si;
            hr2 = a2.x * tr - a2.y * ti + bk2 * v2.x;
            hi2 = a2.x * ti + a2.y * tr + bk2 * v2.y;
            tr = hr3 - bk3 * sr; ti = hi3 - bk3 * si;
            hr3 = a2.x * tr - a2.y * ti + bk3 * v2.x;
            hi3 = a2.x * ti + a2.y * tr + bk3 * v2.y;

            // Y[b,l,h,2m,d]=Re, Y[b,l,h,2m+1,d]=Im — f32x4 nontemporal stores
            const int yb = ((base_l + t) * NH + hh) * (2 * NM * ND);
            f32x4 re; re.x = hr0; re.y = hr1; re.z = hr2; re.w = hr3;
            f32x4 im; im.x = hi0; im.y = hi1; im.z = hi2; im.w = hi3;
            __builtin_nontemporal_store(re, (f32x4*)(Y + yb + (2 * m) * ND + 4 * j));
            __builtin_nontemporal_store(im, (f32x4*)(Y + yb + (2 * m + 1) * ND + 4 * j));
        }
    }
}

extern "C" void kernel_launch(void* const* d_in, const int* in_sizes, int n_in,
                              void* d_out, int out_size, void* d_ws, size_t ws_size,
                              hipStream_t stream) {
    const float* A_bar = (const float*)d_in[0];
    const float* K     = (const float*)d_in[1];
    const float* V     = (const float*)d_in[2];
    const float* beta  = (const float*)d_in[3];
    float* Y = (float*)d_out;

    // ws layout: flags (256 ints) | totalA (16384 f) | buf (1,048,576 f)
    int*   flags  = (int*)d_ws;
    float* totalA = (float*)d_ws + 512;
    float* buf    = (float*)d_ws + 512 + 16384;

    // flags must be zeroed every call (ws persists across graph replays)
    hipMemsetAsync(flags, 0, 256 * sizeof(int), stream);

    void* args[] = {(void*)&A_bar, (void*)&K, (void*)&V, (void*)&beta,
                    (void*)&flags, (void*)&totalA, (void*)&buf, (void*)&Y};
    hipLaunchCooperativeKernel((const void*)fused_kernel,
                               dim3(NC * NH), dim3(512), args, 0, stream);
}

// Round 17
// 45.808 us; speedup vs baseline: 2.3021x; 2.3021x over previous
//
#include <hip/hip_runtime.h>

#define NH 8
#define ND 64
#define NM 32
#define NCH 32   // sub-chunk size
#define NC 32    // num sub-chunks

typedef float f32x4 __attribute__((ext_vector_type(4)));

// ---- 16-lane-group allreduce, pure VALU butterfly (no readlane) ----
__device__ __forceinline__ float grp16_sum(float x) {
    x += __int_as_float(__builtin_amdgcn_update_dpp(0, __float_as_int(x), 0xB1, 0xf, 0xf, false));
    x += __int_as_float(__builtin_amdgcn_update_dpp(0, __float_as_int(x), 0x4E, 0xf, 0xf, false));
    x += __int_as_float(__builtin_amdgcn_update_dpp(0, __float_as_int(x), 0x141, 0xf, 0xf, false));
    x += __int_as_float(__builtin_amdgcn_update_dpp(0, __float_as_int(x), 0x140, 0xf, 0xf, false));
    return x;
}

// ---- 64-lane reduce (DPP rows + readlane bcast) ----
__device__ __forceinline__ float wave_sum_bcast(float x) {
    float s = x;
    s += __int_as_float(__builtin_amdgcn_update_dpp(0, __float_as_int(s), 0x111, 0xf, 0xf, false));
    s += __int_as_float(__builtin_amdgcn_update_dpp(0, __float_as_int(s), 0x112, 0xf, 0xf, false));
    s += __int_as_float(__builtin_amdgcn_update_dpp(0, __float_as_int(s), 0x114, 0xf, 0xf, false));
    s += __int_as_float(__builtin_amdgcn_update_dpp(0, __float_as_int(s), 0x118, 0xf, 0xf, false));
    s += __int_as_float(__builtin_amdgcn_update_dpp(0, __float_as_int(s), 0x142, 0xa, 0xf, false));
    s += __int_as_float(__builtin_amdgcn_update_dpp(0, __float_as_int(s), 0x143, 0xc, 0xf, false));
    return __int_as_float(__builtin_amdgcn_readlane(__float_as_int(s), 63));
}

// ---------------- Kernel A: intra scan, 16-lane groups, Gram-paired steps ----------------
__global__ __launch_bounds__(512) void intra_kernel(
    const float* __restrict__ A_bar, const float* __restrict__ K,
    const float* __restrict__ V, const float* __restrict__ beta,
    float* __restrict__ totalA, float* __restrict__ buf)
{
    __shared__ float K_l[NCH][ND], A_l[NCH][ND], V_l[NCH][ND], b_l[NCH];
    __shared__ float G_l[NCH / 2];
    const int gh = blockIdx.x;       // g*NH + hh
    const int hh = gh & (NH - 1);
    const int g  = gh >> 3;
    const int tid = threadIdx.x;

    {   // stage (512 float4 stagers)
        const int f = tid * 4;
        const int t = f >> 6, off = f & 63;
        const int row = ((g * NCH + t) * NH + hh) * 64 + off;
        *(float4*)&K_l[t][off] = *(const float4*)(K + row);
        *(float4*)&A_l[t][off] = *(const float4*)(A_bar + row);
        *(float4*)&V_l[t][off] = *(const float4*)(V + row);
        if (tid < NCH) b_l[tid] = beta[(g * NCH + tid) * NH + hh];
        __syncthreads();
    }

    const int lane = tid & 63;
    const int r = lane >> 4, j = lane & 15;
    const int m = (tid >> 6) * 4 + r;            // 0..31
    const int grp = tid >> 4;                    // 0..31

    // Gram pairs: G[p] = k_{2p} . k_{2p+1}
    if (grp < NCH / 2) {
        const float4 ka = *(const float4*)(&K_l[2 * grp][4 * j]);
        const float4 kb = *(const float4*)(&K_l[2 * grp + 1][4 * j]);
        float gg = (ka.x * kb.x + ka.y * kb.y) + (ka.z * kb.z + ka.w * kb.w);
        gg = grp16_sum(gg);
        if (j == 0) G_l[grp] = gg;
    }
    __syncthreads();

    float hr0 = 0.f, hr1 = 0.f, hr2 = 0.f, hr3 = 0.f;
    float hi0 = 0.f, hi1 = 0.f, hi2 = 0.f, hi3 = 0.f;
    float cr = 1.f, ci = 0.f;

#pragma unroll 4
    for (int t = 0; t < NCH; t += 2) {
        const float4 ka = *(const float4*)(&K_l[t][4 * j]);
        const float4 kb = *(const float4*)(&K_l[t + 1][4 * j]);
        const float2 aA = *(const float2*)(&A_l[t][2 * m]);
        const float2 aB = *(const float2*)(&A_l[t + 1][2 * m]);
        const float2 vA = *(const float2*)(&V_l[t][2 * m]);
        const float2 vB = *(const float2*)(&V_l[t + 1][2 * m]);
        const float  bA = b_l[t], bB = b_l[t + 1];
        const float  G  = G_l[t >> 1];

        // two independent dot rounds vs the SAME h
        float ura = (hr0 * ka.x + hr1 * ka.y) + (hr2 * ka.z + hr3 * ka.w);
        float uia = (hi0 * ka.x + hi1 * ka.y) + (hi2 * ka.z + hi3 * ka.w);
        float urb = (hr0 * kb.x + hr1 * kb.y) + (hr2 * kb.z + hr3 * kb.w);
        float uib = (hi0 * kb.x + hi1 * kb.y) + (hi2 * kb.z + hi3 * kb.w);
        ura = grp16_sum(ura);  uia = grp16_sum(uia);
        urb = grp16_sum(urb);  uib = grp16_sum(uib);

        // s_t = u_a ; s_{t+1} = aA*(u_b - bA*G*s_t) + bA*G*vA
        const float s1r = ura, s1i = uia;
        const float bAG = bA * G;
        const float xr = urb - bAG * s1r, xi = uib - bAG * s1i;
        const float s2r = aA.x * xr - aA.y * xi + bAG * vA.x;
        const float s2i = aA.x * xi + aA.y * xr + bAG * vA.y;

        // h_t update (k = ka, s = s1, a = aA, v = vA)
        float tr, ti, bk;
        bk = bA * ka.x; tr = hr0 - bk * s1r; ti = hi0 - bk * s1i;
        hr0 = aA.x * tr - aA.y * ti + bk * vA.x;  hi0 = aA.x * ti + aA.y * tr + bk * vA.y;
        bk = bA * ka.y; tr = hr1 - bk * s1r; ti = hi1 - bk * s1i;
        hr1 = aA.x * tr - aA.y * ti + bk * vA.x;  hi1 = aA.x * ti + aA.y * tr + bk * vA.y;
        bk = bA * ka.z; tr = hr2 - bk * s1r; ti = hi2 - bk * s1i;
        hr2 = aA.x * tr - aA.y * ti + bk * vA.x;  hi2 = aA.x * ti + aA.y * tr + bk * vA.y;
        bk = bA * ka.w; tr = hr3 - bk * s1r; ti = hi3 - bk * s1i;
        hr3 = aA.x * tr - aA.y * ti + bk * vA.x;  hi3 = aA.x * ti + aA.y * tr + bk * vA.y;

        // h_{t+1} update (k = kb, s = s2, a = aB, v = vB)
        bk = bB * kb.x; tr = hr0 - bk * s2r; ti = hi0 - bk * s2i;
        hr0 = aB.x * tr - aB.y * ti + bk * vB.x;  hi0 = aB.x * ti + aB.y * tr + bk * vB.y;
        bk = bB * kb.y; tr = hr1 - bk * s2r; ti = hi1 - bk * s2i;
        hr1 = aB.x * tr - aB.y * ti + bk * vB.x;  hi1 = aB.x * ti + aB.y * tr + bk * vB.y;
        bk = bB * kb.z; tr = hr2 - bk * s2r; ti = hi2 - bk * s2i;
        hr2 = aB.x * tr - aB.y * ti + bk * vB.x;  hi2 = aB.x * ti + aB.y * tr + bk * vB.y;
        bk = bB * kb.w; tr = hr3 - bk * s2r; ti = hi3 - bk * s2i;
        hr3 = aB.x * tr - aB.y * ti + bk * vB.x;  hi3 = aB.x * ti + aB.y * tr + bk * vB.y;

        // cumA *= aA then aB
        float n;
        n = cr * aA.x - ci * aA.y; ci = cr * aA.y + ci * aA.x; cr = n;
        n = cr * aB.x - ci * aB.y; ci = cr * aB.y + ci * aB.x; cr = n;
    }

    const int base_m = gh * NM + m;              // entry id
    *(float4*)&buf[base_m * 128 + 4 * j]      = make_float4(hr0, hr1, hr2, hr3);
    *(float4*)&buf[base_m * 128 + 64 + 4 * j] = make_float4(hi0, hi1, hi2, hi3);
    if (j == 0) {
        totalA[2 * base_m]     = cr;
        totalA[2 * base_m + 1] = ci;
    }
}

// ---------------- Kernel B: prefix + final scan (64-lane pair-waves, Gram-paired) ----------------
__global__ __launch_bounds__(256) void final_kernel(
    const float* __restrict__ A_bar, const float* __restrict__ K,
    const float* __restrict__ V, const float* __restrict__ beta,
    const float* __restrict__ totalA, const float* __restrict__ buf,
    float* __restrict__ Y)
{
    __shared__ float K_l[NCH][ND], A_l[NCH][ND], V_l[NCH][ND], b_l[NCH];
    __shared__ float G_l[NCH / 2];
    const int w  = blockIdx.x * 4 + (threadIdx.x >> 6);  // pair-wave id
    const int p  = w & 15;                               // rows p, p+16
    const int hh = (w >> 4) & (NH - 1);
    const int g  = w >> 7;
    const int lane = threadIdx.x & 63;
    const int wv = threadIdx.x >> 6;                     // wave in block 0..3

    {   // stage (256 threads, 8 floats each)
        const int tid = threadIdx.x;
        const int f   = tid * 8;
        const int t   = f >> 6, off = f & 63;
        const int row = ((g * NCH + t) * NH + hh) * 64 + off;
        *(float4*)&K_l[t][off]     = *(const float4*)(K + row);
        *(float4*)&K_l[t][off + 4] = *(const float4*)(K + row + 4);
        *(float4*)&A_l[t][off]     = *(const float4*)(A_bar + row);
        *(float4*)&A_l[t][off + 4] = *(const float4*)(A_bar + row + 4);
        *(float4*)&V_l[t][off]     = *(const float4*)(V + row);
        *(float4*)&V_l[t][off + 4] = *(const float4*)(V + row + 4);
        if (tid < NCH) b_l[tid] = beta[(g * NCH + tid) * NH + hh];
        __syncthreads();
    }

    // Gram pairs, 4 per wave
#pragma unroll
    for (int q = 0; q < 4; ++q) {
        const int pr = wv * 4 + q;                      // 0..15
        const float gg = wave_sum_bcast(K_l[2 * pr][lane] * K_l[2 * pr + 1][lane]);
        if (lane == 0) G_l[pr] = gg;
    }
    __syncthreads();

    // ---- prefix: fold s = A_gg * s + H_gg over gg < g ----
    float hr0 = 0.f, hi0 = 0.f, hr1 = 0.f, hi1 = 0.f;
    for (int gg = 0; gg < g; ++gg) {
        const int e0 = (gg * NH + hh) * NM + p;
        const int e1 = e0 + 16;
        const float a0r = totalA[2 * e0], a0i = totalA[2 * e0 + 1];
        const float a1r = totalA[2 * e1], a1i = totalA[2 * e1 + 1];
        const float f0r = buf[e0 * 128 + lane], f0i = buf[e0 * 128 + 64 + lane];
        const float f1r = buf[e1 * 128 + lane], f1i = buf[e1 * 128 + 64 + lane];
        float n;
        n = a0r * hr0 - a0i * hi0 + f0r;  hi0 = a0r * hi0 + a0i * hr0 + f0i;  hr0 = n;
        n = a1r * hr1 - a1i * hi1 + f1r;  hi1 = a1r * hi1 + a1i * hr1 + f1i;  hr1 = n;
    }

    // ---- final scan, Gram-paired; state IS the output ----
    const int base_l = g * NCH;
#pragma unroll 4
    for (int t = 0; t < NCH; t += 2) {
        const float kda = K_l[t][lane], kdb = K_l[t + 1][lane];
        const float bA = b_l[t], bB = b_l[t + 1];
        const float G  = G_l[t >> 1];
        const float2 a0A = *(const float2*)(&A_l[t][2 * p]);
        const float2 a0B = *(const float2*)(&A_l[t + 1][2 * p]);
        const float2 v0A = *(const float2*)(&V_l[t][2 * p]);
        const float2 v0B = *(const float2*)(&V_l[t + 1][2 * p]);
        const float2 a1A = *(const float2*)(&A_l[t][2 * (p + 16)]);
        const float2 a1B = *(const float2*)(&A_l[t + 1][2 * (p + 16)]);
        const float2 v1A = *(const float2*)(&V_l[t][2 * (p + 16)]);
        const float2 v1B = *(const float2*)(&V_l[t + 1][2 * (p + 16)]);

        // 8 independent reductions vs the same states
        const float r0a = wave_sum_bcast(hr0 * kda);
        const float i0a = wave_sum_bcast(hi0 * kda);
        const float r0b = wave_sum_bcast(hr0 * kdb);
        const float i0b = wave_sum_bcast(hi0 * kdb);
        const float r1a = wave_sum_bcast(hr1 * kda);
        const float i1a = wave_sum_bcast(hi1 * kda);
        const float r1b = wave_sum_bcast(hr1 * kdb);
        const float i1b = wave_sum_bcast(hi1 * kdb);

        const float bAG = bA * G;
        // row 0: s1 = (r0a,i0a); s2 = a0A*(u_b - bAG*s1) + bAG*v0A
        const float x0r = r0b - bAG * r0a, x0i = i0b - bAG * i0a;
        const float s20r = a0A.x * x0r - a0A.y * x0i + bAG * v0A.x;
        const float s20i = a0A.x * x0i + a0A.y * x0r + bAG * v0A.y;
        // row 1
        const float x1r = r1b - bAG * r1a, x1i = i1b - bAG * i1a;
        const float s21r = a1A.x * x1r - a1A.y * x1i + bAG * v1A.x;
        const float s21i = a1A.x * x1i + a1A.y * x1r + bAG * v1A.y;

        float tr, ti, bk;
        const int yb0 = ((base_l + t) * NH + hh) * (2 * NM) * ND + lane;
        const int yb1 = yb0 + NH * (2 * NM) * ND;

        // step t, row 0
        bk = bA * kda;
        tr = hr0 - bk * r0a; ti = hi0 - bk * i0a;
        hr0 = a0A.x * tr - a0A.y * ti + bk * v0A.x;
        hi0 = a0A.x * ti + a0A.y * tr + bk * v0A.y;
        __builtin_nontemporal_store(hr0, &Y[yb0 + (2 * p) * ND]);
        __builtin_nontemporal_store(hi0, &Y[yb0 + (2 * p + 1) * ND]);
        // step t, row 1
        tr = hr1 - bk * r1a; ti = hi1 - bk * i1a;
        hr1 = a1A.x * tr - a1A.y * ti + bk * v1A.x;
        hi1 = a1A.x * ti + a1A.y * tr + bk * v1A.y;
        __builtin_nontemporal_store(hr1, &Y[yb0 + (2 * (p + 16)) * ND]);
        __builtin_nontemporal_store(hi1, &Y[yb0 + (2 * (p + 16) + 1) * ND]);

        // step t+1, row 0
        bk = bB * kdb;
        tr = hr0 - bk * s20r; ti = hi0 - bk * s20i;
        hr0 = a0B.x * tr - a0B.y * ti + bk * v0B.x;
        hi0 = a0B.x * ti + a0B.y * tr + bk * v0B.y;
        __builtin_nontemporal_store(hr0, &Y[yb1 + (2 * p) * ND]);
        __builtin_nontemporal_store(hi0, &Y[yb1 + (2 * p + 1) * ND]);
        // step t+1, row 1
        tr = hr1 - bk * s21r; ti = hi1 - bk * s21i;
        hr1 = a1B.x * tr - a1B.y * ti + bk * v1B.x;
        hi1 = a1B.x * ti + a1B.y * tr + bk * v1B.y;
        __builtin_nontemporal_store(hr1, &Y[yb1 + (2 * (p + 16)) * ND]);
        __builtin_nontemporal_store(hi1, &Y[yb1 + (2 * (p + 16) + 1) * ND]);
    }
}

extern "C" void kernel_launch(void* const* d_in, const int* in_sizes, int n_in,
                              void* d_out, int out_size, void* d_ws, size_t ws_size,
                              hipStream_t stream) {
    const float* A_bar = (const float*)d_in[0];
    const float* K     = (const float*)d_in[1];
    const float* V     = (const float*)d_in[2];
    const float* beta  = (const float*)d_in[3];
    float* Y = (float*)d_out;

    float* ws = (float*)d_ws;
    float* totalA = ws;                 // NC*NH*NM*2 = 16384 floats
    float* buf    = ws + 16384;         // finalH planar: 1,048,576 floats (4 MB)

    intra_kernel<<<NC * NH, 512, 0, stream>>>(A_bar, K, V, beta, totalA, buf);
    const int nwave = NC * NH * (NM / 2);       // 4096 pair-waves
    final_kernel<<<nwave / 4, 256, 0, stream>>>(A_bar, K, V, beta, totalA, buf, Y);
}